// Round 5
// baseline (430.679 us; speedup 1.0000x reference)
//
#include <hip/hip_runtime.h>

typedef _Float16 half8 __attribute__((ext_vector_type(8)));
typedef _Float16 half4t __attribute__((ext_vector_type(4)));
typedef _Float16 half2t __attribute__((ext_vector_type(2)));
typedef float float4t __attribute__((ext_vector_type(4)));
typedef float float4u __attribute__((ext_vector_type(4), aligned(4)));

#define BATCH 32
#define CIN 64
#define HIN 128
#define WIN 128
#define COUT 128
#define HOUT 126
#define WOUT 126
#define HP 63
#define WP 63
#define NGROUPS 16
#define CPG 8
#define EPSV 1e-5f

// xp row: 130 cols x 64 cins fp16 = 16640 B (8320 elems)
#define XPR 8320
#define XPRB 16640

// wT[pos][cout][cin] fp16, pos = kh*3+kw
__global__ __launch_bounds__(256) void wt_kernel(const float* __restrict__ w,
                                                 _Float16* __restrict__ wT) {
    int idx = blockIdx.x * 256 + threadIdx.x;
    if (idx >= 9 * COUT * CIN) return;
    int cin = idx & 63;
    int t = idx >> 6;
    int cout = t & 127;
    int pos = t >> 7;
    wT[idx] = (_Float16)w[(cout * CIN + cin) * 9 + pos];
}

// Repack x NCHW fp32 -> xp[b][grow][col(130)][cin(64)] fp16, PRE-SWIZZLED:
// cin-chunk chk (8 cins) of (grow,col) stored at slot chk ^ ((2*grow+col)&7).
// LDS stride 72 (144B, 16B-aligned): b128 slot reads legal; 16B global stores.
__global__ __launch_bounds__(256) void repack_kernel(const float* __restrict__ x,
                                                     _Float16* __restrict__ xp) {
    __shared__ _Float16 lt[128 * 72];   // 18,432 B
    const int tid = threadIdx.x;
    const int grow = blockIdx.x;
    const int b = blockIdx.y;

    const int u = tid >> 5;             // 0..7
    const int col0 = (tid & 31) * 4;
    const float* xb = x + ((size_t)b * CIN * HIN + grow) * WIN;
#pragma unroll
    for (int i = 0; i < 4; i++) {
        int cin0 = 2 * (u + 8 * i);
        float4t va = *(const float4t*)(xb + (size_t)cin0 * HIN * WIN + col0);
        float4t vb = *(const float4t*)(xb + (size_t)(cin0 + 1) * HIN * WIN + col0);
#pragma unroll
        for (int j = 0; j < 4; j++) {
            half2t hv = { (_Float16)va[j], (_Float16)vb[j] };
            *(half2t*)&lt[(col0 + j) * 72 + cin0] = hv;   // b32 write, 4-way: cheap
        }
    }
    __syncthreads();

    _Float16* xpb = xp + ((size_t)b * HIN + grow) * XPR;
#pragma unroll
    for (int k = 0; k < 4; k++) {
        int cidx = tid + 256 * k;        // 0..1023 -> (col 0..127, chk 0..7)
        int col = cidx >> 3, chk = cidx & 7;
        half8 v = *(const half8*)&lt[col * 72 + chk * 8];   // aligned b128
        int slot = chk ^ ((2 * grow + col) & 7);
        *(half8*)(xpb + col * 64 + slot * 8) = v;           // 16B store
    }
    if (tid < 16) {                      // pad cols 128,129 = zeros
        int col = 128 + (tid >> 3), chk = tid & 7;
        int slot = chk ^ ((2 * grow + col) & 7);
        half8 z;
#pragma unroll
        for (int j = 0; j < 8; j++) z[j] = (_Float16)0.f;
        *(half8*)(xpb + col * 64 + slot * 8) = z;
    }
}

// Conv: 512 threads / 8 waves = (w2 cout-half) x (nh pixel-half) x (row 0/1).
// 4 staged xp rows (one linear 66,560B copy), ONE barrier before K-loop.
// 4 waves/SIMD (VGPR capped 128). Pool: horizontal in-register; vertical combine
// via LDS scratch (reusing xs after a barrier); store pooled {max,min} fp16 pairs.
__global__ __launch_bounds__(512, 4) void conv_mfma_kernel(
    const _Float16* __restrict__ xp, const _Float16* __restrict__ wT,
    const float* __restrict__ bias, unsigned int* __restrict__ pl,
    float* __restrict__ stats)
{
    __shared__ __align__(16) _Float16 xs[4 * XPR];   // 66,560 B

    const int tid = threadIdx.x;
    // XCD-chunked remap (bijective: 2016 = 8*252)
    int f = blockIdx.y * 63 + blockIdx.x;
    int w = (f & 7) * 252 + (f >> 3);
    const int s = w % 63;
    const int b = w / 63;
    const int oy = 2 * s;

    const int lane = tid & 63;
    const int wv = tid >> 6;          // 0..7
    const int w2 = wv & 1;            // cout half
    const int nh = (wv >> 1) & 1;     // pixel half
    const int row = wv >> 2;          // output row 0/1
    const int m = lane & 15;
    const int q = lane >> 4;
    const int cb = w2 * 64;

    // ---- stage: rows oy..oy+3 are contiguous in xp -> one 66,560B linear copy ----
    {
        const char* src = (const char*)(xp + ((size_t)b * HIN + oy) * XPR);
#pragma unroll
        for (int k = 0; k < 8; k++) {
            int chunk = wv * 8 + k;   // 0..63
            __builtin_amdgcn_global_load_lds(
                (const __attribute__((address_space(1))) void*)(src + chunk * 1024 + lane * 16),
                (__attribute__((address_space(3))) void*)((char*)xs + chunk * 1024), 16, 0, 0);
        }
        if (wv == 0) {
            __builtin_amdgcn_global_load_lds(
                (const __attribute__((address_space(1))) void*)(src + 65536 + lane * 16),
                (__attribute__((address_space(3))) void*)((char*)xs + 65536), 16, 0, 0);
        }
    }

    float bv[4];
#pragma unroll
    for (int sub = 0; sub < 4; sub++) bv[sub] = bias[cb + sub * 16 + m];

    float4t acc[4][4];
#pragma unroll
    for (int sub = 0; sub < 4; sub++)
#pragma unroll
        for (int n = 0; n < 4; n++)
            acc[sub][n] = (float4t){0.f, 0.f, 0.f, 0.f};

    __syncthreads();

    const int r = oy + row;
#pragma unroll
    for (int kk = 0; kk < 18; kk++) {
        const int pos = kk >> 1, ch = kk & 1;
        const int kh = (pos > 2) + (pos > 5);
        const int kw = pos - kh * 3;
        int key = (2 * (r + kh) + m + kw) & 7;
        const _Float16* bb = &xs[(row + kh) * XPR + (m + kw) * 64 + (((q + 4 * ch) ^ key) << 3)];

        half8 aw[4];
#pragma unroll
        for (int sub = 0; sub < 4; sub++)
            aw[sub] = *(const half8*)(wT + ((size_t)(pos * COUT + cb + sub * 16 + m)) * CIN + q * 8 + ch * 32);

#pragma unroll
        for (int n = 0; n < 4; n++) {
            half8 bf = *(const half8*)(bb + (nh * 4 + n) * 1024);
#pragma unroll
            for (int sub = 0; sub < 4; sub++)
                acc[sub][n] = __builtin_amdgcn_mfma_f32_16x16x32_f16(bf, aw[sub], acc[sub][n], 0, 0, 0);
        }
    }

    // ---- epilogue: bias, stats, horizontal pool in-register ----
    float sv[4] = {0.f, 0.f, 0.f, 0.f}, ssv[4] = {0.f, 0.f, 0.f, 0.f};
    half4t hmm[4][4];
#pragma unroll
    for (int sub = 0; sub < 4; sub++) {
#pragma unroll
        for (int n = 0; n < 4; n++) {
            int pix0 = (nh * 4 + n) * 16 + q * 4;
            float p0 = acc[sub][n][0] + bv[sub];
            float p1 = acc[sub][n][1] + bv[sub];
            float p2 = acc[sub][n][2] + bv[sub];
            float p3 = acc[sub][n][3] + bv[sub];
            sv[sub]  += p0 + p1;
            ssv[sub] += p0 * p0 + p1 * p1;
            if (pix0 != 124) {      // only (nh=1,n=3,q=3): pixels 126/127 invalid
                sv[sub]  += p2 + p3;
                ssv[sub] += p2 * p2 + p3 * p3;
            }
            float mx0 = fmaxf(p0, p1), mn0 = fminf(p0, p1);
            float mx1 = fmaxf(p2, p3), mn1 = fminf(p2, p3);
            hmm[sub][n] = (half4t){ (_Float16)mx0, (_Float16)mn0,
                                    (_Float16)mx1, (_Float16)mn1 };
        }
    }

    // ---- vertical pool combine across row-waves via LDS scratch (reuse xs) ----
    __syncthreads();                      // all xs reads for K-loop complete
    half4t* sc = (half4t*)xs;             // 32 KB used
    if (row == 1) {
#pragma unroll
        for (int sub = 0; sub < 4; sub++)
#pragma unroll
            for (int n = 0; n < 4; n++)
                sc[(((wv & 3) * 4 + sub) * 4 + n) * 64 + lane] = hmm[sub][n];
    }
    __syncthreads();
    if (row == 0) {
#pragma unroll
        for (int sub = 0; sub < 4; sub++) {
            const int c = cb + sub * 16 + m;
#pragma unroll
            for (int n = 0; n < 4; n++) {
                half4t o2 = sc[(((wv & 3) * 4 + sub) * 4 + n) * 64 + lane];
                half4t h = hmm[sub][n];
                half4t o = { h[0] > o2[0] ? h[0] : o2[0],
                             h[1] < o2[1] ? h[1] : o2[1],
                             h[2] > o2[2] ? h[2] : o2[2],
                             h[3] < o2[3] ? h[3] : o2[3] };
                unsigned int* dst = pl + (((size_t)b * COUT + c) * HP + s) * 64
                                    + (nh * 4 + n) * 8 + 2 * q;
                *(half4t*)dst = o;      // 8B; pooled col 63 garbage, never read
            }
        }
    }

    // ---- stats: both row-waves contribute; reduce lane bits {0,1,2,4,5} ----
#pragma unroll
    for (int sub = 0; sub < 4; sub++) {
        float aa = sv[sub], cc = ssv[sub];
        aa += __shfl_xor(aa, 1);  cc += __shfl_xor(cc, 1);
        aa += __shfl_xor(aa, 2);  cc += __shfl_xor(cc, 2);
        aa += __shfl_xor(aa, 4);  cc += __shfl_xor(cc, 4);
        aa += __shfl_xor(aa, 16); cc += __shfl_xor(cc, 16);
        aa += __shfl_xor(aa, 32); cc += __shfl_xor(cc, 32);
        if ((lane & 55) == 0) {   // lanes 0 and 8
            int g = w2 * 8 + sub * 2 + ((lane >> 3) & 1);
            atomicAdd(&stats[(b * NGROUPS + g) * 2 + 0], aa);
            atomicAdd(&stats[(b * NGROUPS + g) * 2 + 1], cc);
        }
    }
}

// pl entry = half2 {mx, mn} per pooled col. out = max(A*mx+B, A*mn+B): exact for
// either sign of A.
__global__ __launch_bounds__(256) void norm_pool_kernel(
    const unsigned int* __restrict__ pl, const float* __restrict__ stats,
    const float* __restrict__ gnw, const float* __restrict__ gnb,
    const float* __restrict__ scale, float* __restrict__ out)
{
    const int t  = threadIdx.x & 15;        // pooled cols 4t..4t+3
    const int hs = threadIdx.x >> 4;
    const int hblk = blockIdx.x & 3;
    const int c = (blockIdx.x >> 2) & 127;
    const int b = blockIdx.x >> 9;
    const int hp = hblk * 16 + hs;

    const float N = (float)(CPG * HOUT * WOUT);
    int g = c >> 3;
    float sum   = stats[(b * NGROUPS + g) * 2 + 0];
    float sumsq = stats[(b * NGROUPS + g) * 2 + 1];
    float mean = sum / N;
    float var  = sumsq / N - mean * mean;
    float rstd = rsqrtf(var + EPSV);

    float gw = gnw[c] * rstd;
    float A  = gw * scale[c];
    float B2 = (gnb[c] - mean * gw) * scale[c];

    if (hp >= HP) return;

    const unsigned int* yp = pl + (((size_t)b * COUT + c) * HP + hp) * 64 + t * 4;
    half8 rv = *(const half8*)yp;   // 4 entries = {mx,mn}x4

    float o[4];
#pragma unroll
    for (int j = 0; j < 4; j++) {
        float vx = fmaf((float)rv[2 * j],     A, B2);
        float vn = fmaf((float)rv[2 * j + 1], A, B2);
        float mx = fmaxf(vx, vn);
        o[j] = fminf(fmaxf(mx, 0.0f), 1.0f);
    }

    float* op = out + (((size_t)b * COUT + c) * HP + hp) * WP + t * 4;
    if (t < 15) {
        *(float4u*)op = (float4u){o[0], o[1], o[2], o[3]};
    } else {          // pooled cols 60,61,62 valid; 63 is pad
        op[0] = o[0]; op[1] = o[1]; op[2] = o[2];
    }
}

extern "C" void kernel_launch(void* const* d_in, const int* in_sizes, int n_in,
                              void* d_out, int out_size, void* d_ws, size_t ws_size,
                              hipStream_t stream) {
    const float* x      = (const float*)d_in[0];
    const float* conv_w = (const float*)d_in[1];
    const float* conv_b = (const float*)d_in[2];
    const float* gnw    = (const float*)d_in[3];
    const float* gnb    = (const float*)d_in[4];
    const float* scale  = (const float*)d_in[5];
    float* out = (float*)d_out;

    const size_t pl_bytes = (size_t)BATCH * COUT * HP * 64 * 4;   // 66.1 MB
    unsigned int* pl = (unsigned int*)d_ws;
    float* stats = (float*)((char*)d_ws + pl_bytes);              // 4 KB reserved
    _Float16* wT = (_Float16*)((char*)d_ws + pl_bytes + 4096);    // 147,456 B
    _Float16* xp = (_Float16*)((char*)d_ws + pl_bytes + 4096 + 147456); // 68.2 MB

    hipMemsetAsync(stats, 0, BATCH * NGROUPS * 2 * sizeof(float), stream);

    wt_kernel<<<(9 * COUT * CIN + 255) / 256, 256, 0, stream>>>(conv_w, wT);

    dim3 rgrid(HIN, BATCH);
    repack_kernel<<<rgrid, 256, 0, stream>>>(x, xp);

    dim3 grid(HP, BATCH);   // 63 x 32 = 2016 blocks, 512 threads
    conv_mfma_kernel<<<grid, 512, 0, stream>>>(xp, wT, conv_b, pl, stats);

    norm_pool_kernel<<<BATCH * COUT * 4, 256, 0, stream>>>(
        pl, stats, gnw, gnb, scale, out);
}

// Round 6
// 362.850 us; speedup vs baseline: 1.1869x; 1.1869x over previous
//
#include <hip/hip_runtime.h>

typedef _Float16 half8 __attribute__((ext_vector_type(8)));
typedef _Float16 half4t __attribute__((ext_vector_type(4)));
typedef _Float16 half2t __attribute__((ext_vector_type(2)));
typedef float float4t __attribute__((ext_vector_type(4)));
typedef float float4u __attribute__((ext_vector_type(4), aligned(4)));

#define BATCH 32
#define CIN 64
#define HIN 128
#define WIN 128
#define COUT 128
#define HOUT 126
#define WOUT 126
#define HP 63
#define WP 63
#define NGROUPS 16
#define CPG 8
#define EPSV 1e-5f

// xp row: 130 cols x 64 cins fp16 = 16640 B (8320 elems)
#define XPR 8320
#define XPRB 16640

// Fused prep kernel. grid (137, 32):
//   x < 128 : repack block (grow = x, b = y) — LDS-free transpose.
//   x >= 128: wt block (pos = x-128, grp = y); block (128,0) also zeroes stats.
// Repack: thread (colq=tid>>3, chk=tid&7) owns cols 4*colq..+3 for cins 8*chk..+7.
// Reads 8x float4 (128B/cin contiguous per instr), writes 4x half8; the 8 chk-lanes
// of a col assemble the full swizzled 128B row: slot = chk ^ ((2*grow+col)&7).
__global__ __launch_bounds__(256) void prep_kernel(
    const float* __restrict__ x, const float* __restrict__ w,
    _Float16* __restrict__ xp, _Float16* __restrict__ wT,
    float* __restrict__ stats)
{
    const int tid = threadIdx.x;
    if (blockIdx.x >= 128) {
        // ---- weight transform: wT[pos][cout][cin] ----
        const int pos = blockIdx.x - 128;
        const int idx = blockIdx.y * 256 + tid;   // 0..8191 = cout*64+cin
        const int cout = idx >> 6, cin = idx & 63;
        wT[pos * (COUT * CIN) + idx] = (_Float16)w[(cout * CIN + cin) * 9 + pos];
        if (blockIdx.x == 128 && blockIdx.y == 0)
            ((float4t*)stats)[tid] = (float4t){0.f, 0.f, 0.f, 0.f};   // 1024 floats
        return;
    }

    const int grow = blockIdx.x;
    const int b = blockIdx.y;
    const int colq = tid >> 3;       // 0..31 -> cols 4*colq..4*colq+3
    const int chk  = tid & 7;        // cin chunk (8 cins)
    const int c0 = colq * 4;

    const float* xb = x + (((size_t)b * CIN + chk * 8) * HIN + grow) * WIN + c0;
    float4t v[8];
#pragma unroll
    for (int i = 0; i < 8; i++)
        v[i] = *(const float4t*)(xb + (size_t)i * HIN * WIN);

    _Float16* xpb = xp + ((size_t)b * HIN + grow) * XPR;
#pragma unroll
    for (int j = 0; j < 4; j++) {
        int col = c0 + j;
        int slot = chk ^ ((2 * grow + col) & 7);
        half8 h = { (_Float16)v[0][j], (_Float16)v[1][j], (_Float16)v[2][j],
                    (_Float16)v[3][j], (_Float16)v[4][j], (_Float16)v[5][j],
                    (_Float16)v[6][j], (_Float16)v[7][j] };
        *(half8*)(xpb + col * 64 + slot * 8) = h;   // 16B; 8 chk-lanes = 128B row
    }
    if (tid < 16) {                  // pad cols 128,129 = zeros
        int col = 128 + (tid >> 3), ck = tid & 7;
        int slot = ck ^ ((2 * grow + col) & 7);
        half8 z;
#pragma unroll
        for (int j = 0; j < 8; j++) z[j] = (_Float16)0.f;
        *(half8*)(xpb + col * 64 + slot * 8) = z;
    }
}

// Conv (R4 structure): 2 output rows (one pooled row) per block, 256 thr / 4 waves.
// Stage 4 xp rows (66,560 B), ONE barrier, both rows in the same kk loop (weights
// shared via prefetch ring). Epilogue: bias, stats, full 2x2 pool in-register,
// store pooled {max,min} fp16 pairs. Grid 63 x 32 = 2016 blocks, 2 blocks/CU.
__global__ __launch_bounds__(256, 2) void conv_mfma_kernel(
    const _Float16* __restrict__ xp, const _Float16* __restrict__ wT,
    const float* __restrict__ bias, unsigned int* __restrict__ pl,
    float* __restrict__ stats)
{
    __shared__ __align__(16) _Float16 xs[4 * XPR];   // 66,560 B

    const int tid = threadIdx.x;
    // XCD-chunked remap (bijective: 2016 = 8*252)
    int f = blockIdx.y * 63 + blockIdx.x;
    int w = (f & 7) * 252 + (f >> 3);
    const int s = w % 63;
    const int b = w / 63;
    const int oy = 2 * s;

    const int lane = tid & 63;
    const int wv = tid >> 6;
    const int w2 = wv & 1;        // cout half
    const int nh = wv >> 1;       // pixel half
    const int m = lane & 15;
    const int q = lane >> 4;
    const int cb = w2 * 64;

    // ---- stage: rows oy..oy+3 contiguous in xp -> linear 66,560B copy ----
    {
        const char* src = (const char*)(xp + ((size_t)b * HIN + oy) * XPR);
#pragma unroll
        for (int k = 0; k < 16; k++) {
            int chunk = wv * 16 + k;   // 0..63
            __builtin_amdgcn_global_load_lds(
                (const __attribute__((address_space(1))) void*)(src + chunk * 1024 + lane * 16),
                (__attribute__((address_space(3))) void*)((char*)xs + chunk * 1024), 16, 0, 0);
        }
        if (wv == 0) {
            __builtin_amdgcn_global_load_lds(
                (const __attribute__((address_space(1))) void*)(src + 65536 + lane * 16),
                (__attribute__((address_space(3))) void*)((char*)xs + 65536), 16, 0, 0);
        }
    }

    half8 a[4], na[4];
#pragma unroll
    for (int sub = 0; sub < 4; sub++)
        a[sub] = *(const half8*)(wT + ((size_t)(cb + sub * 16 + m)) * CIN + q * 8);

    float bv[4];
#pragma unroll
    for (int sub = 0; sub < 4; sub++) bv[sub] = bias[cb + sub * 16 + m];

    float4t acc0[4][4], acc1[4][4];
#pragma unroll
    for (int sub = 0; sub < 4; sub++)
#pragma unroll
        for (int n = 0; n < 4; n++) {
            acc0[sub][n] = (float4t){0.f, 0.f, 0.f, 0.f};
            acc1[sub][n] = (float4t){0.f, 0.f, 0.f, 0.f};
        }

    __syncthreads();

    for (int kk = 0; kk < 18; kk++) {
        int pos = kk >> 1, ch = kk & 1;
        int kh = (pos > 2) + (pos > 5);
        int kw = pos - kh * 3;
        int key0 = (2 * (oy + kh) + m + kw) & 7;        // row oy+kh   -> xs[kh]
        int key1 = (key0 + 2) & 7;                      // row oy+1+kh -> xs[kh+1]
        const _Float16* b0 = &xs[kh * XPR + (m + kw) * 64 + (((q + 4 * ch) ^ key0) << 3)];
        const _Float16* b1 = &xs[(kh + 1) * XPR + (m + kw) * 64 + (((q + 4 * ch) ^ key1) << 3)];

#pragma unroll
        for (int sub = 0; sub < 4; sub++) na[sub] = a[sub];
        if (kk < 17) {
            int nk = kk + 1, npos = nk >> 1, nch = nk & 1;
#pragma unroll
            for (int sub = 0; sub < 4; sub++)
                na[sub] = *(const half8*)(wT + ((size_t)(npos * COUT + cb + sub * 16 + m)) * CIN + q * 8 + nch * 32);
        }

#pragma unroll
        for (int n = 0; n < 4; n++) {
            half8 bf0 = *(const half8*)(b0 + (nh * 4 + n) * 1024);
            half8 bf1 = *(const half8*)(b1 + (nh * 4 + n) * 1024);
#pragma unroll
            for (int sub = 0; sub < 4; sub++) {
                acc0[sub][n] = __builtin_amdgcn_mfma_f32_16x16x32_f16(bf0, a[sub], acc0[sub][n], 0, 0, 0);
                acc1[sub][n] = __builtin_amdgcn_mfma_f32_16x16x32_f16(bf1, a[sub], acc1[sub][n], 0, 0, 0);
            }
        }
#pragma unroll
        for (int sub = 0; sub < 4; sub++) a[sub] = na[sub];
    }

    // ---- epilogue: bias, stats (both rows), 2x2 pool -> {max,min} fp16 pairs ----
    float sv[4] = {0.f, 0.f, 0.f, 0.f}, ssv[4] = {0.f, 0.f, 0.f, 0.f};
#pragma unroll
    for (int sub = 0; sub < 4; sub++) {
        const int c = cb + sub * 16 + m;
#pragma unroll
        for (int n = 0; n < 4; n++) {
            int pix0 = (nh * 4 + n) * 16 + q * 4;
            float p00 = acc0[sub][n][0] + bv[sub];
            float p01 = acc0[sub][n][1] + bv[sub];
            float p02 = acc0[sub][n][2] + bv[sub];
            float p03 = acc0[sub][n][3] + bv[sub];
            float p10 = acc1[sub][n][0] + bv[sub];
            float p11 = acc1[sub][n][1] + bv[sub];
            float p12 = acc1[sub][n][2] + bv[sub];
            float p13 = acc1[sub][n][3] + bv[sub];
            sv[sub]  += p00 + p01 + p10 + p11;
            ssv[sub] += p00 * p00 + p01 * p01 + p10 * p10 + p11 * p11;
            if (pix0 != 124) {      // only (nh=1,n=3,q=3): pixels 126/127 invalid
                sv[sub]  += p02 + p03 + p12 + p13;
                ssv[sub] += p02 * p02 + p03 * p03 + p12 * p12 + p13 * p13;
            }
            float mx0 = fmaxf(fmaxf(p00, p01), fmaxf(p10, p11));
            float mn0 = fminf(fminf(p00, p01), fminf(p10, p11));
            float mx1 = fmaxf(fmaxf(p02, p03), fmaxf(p12, p13));
            float mn1 = fminf(fminf(p02, p03), fminf(p12, p13));
            half4t o = { (_Float16)mx0, (_Float16)mn0, (_Float16)mx1, (_Float16)mn1 };
            unsigned int* dst = pl + (((size_t)b * COUT + c) * HP + s) * 64
                                + (nh * 4 + n) * 8 + 2 * q;
            *(half4t*)dst = o;      // 8B; pooled col 63 garbage, never read
        }
    }

    // ---- stats: reduce over lane bits {0,1,2,4,5}, atomic once per block ----
#pragma unroll
    for (int sub = 0; sub < 4; sub++) {
        float aa = sv[sub], cc = ssv[sub];
        aa += __shfl_xor(aa, 1);  cc += __shfl_xor(cc, 1);
        aa += __shfl_xor(aa, 2);  cc += __shfl_xor(cc, 2);
        aa += __shfl_xor(aa, 4);  cc += __shfl_xor(cc, 4);
        aa += __shfl_xor(aa, 16); cc += __shfl_xor(cc, 16);
        aa += __shfl_xor(aa, 32); cc += __shfl_xor(cc, 32);
        if ((lane & 55) == 0) {   // lanes 0 and 8
            int g = w2 * 8 + sub * 2 + ((lane >> 3) & 1);
            atomicAdd(&stats[(b * NGROUPS + g) * 2 + 0], aa);
            atomicAdd(&stats[(b * NGROUPS + g) * 2 + 1], cc);
        }
    }
}

// pl entry = half2 {mx, mn} per pooled col. out = max(A*mx+B, A*mn+B): exact for
// either sign of A.
__global__ __launch_bounds__(256) void norm_pool_kernel(
    const unsigned int* __restrict__ pl, const float* __restrict__ stats,
    const float* __restrict__ gnw, const float* __restrict__ gnb,
    const float* __restrict__ scale, float* __restrict__ out)
{
    const int t  = threadIdx.x & 15;        // pooled cols 4t..4t+3
    const int hs = threadIdx.x >> 4;
    const int hblk = blockIdx.x & 3;
    const int c = (blockIdx.x >> 2) & 127;
    const int b = blockIdx.x >> 9;
    const int hp = hblk * 16 + hs;

    const float N = (float)(CPG * HOUT * WOUT);
    int g = c >> 3;
    float sum   = stats[(b * NGROUPS + g) * 2 + 0];
    float sumsq = stats[(b * NGROUPS + g) * 2 + 1];
    float mean = sum / N;
    float var  = sumsq / N - mean * mean;
    float rstd = rsqrtf(var + EPSV);

    float gw = gnw[c] * rstd;
    float A  = gw * scale[c];
    float B2 = (gnb[c] - mean * gw) * scale[c];

    if (hp >= HP) return;

    const unsigned int* yp = pl + (((size_t)b * COUT + c) * HP + hp) * 64 + t * 4;
    half8 rv = *(const half8*)yp;   // 4 entries = {mx,mn}x4

    float o[4];
#pragma unroll
    for (int j = 0; j < 4; j++) {
        float vx = fmaf((float)rv[2 * j],     A, B2);
        float vn = fmaf((float)rv[2 * j + 1], A, B2);
        float mx = fmaxf(vx, vn);
        o[j] = fminf(fmaxf(mx, 0.0f), 1.0f);
    }

    float* op = out + (((size_t)b * COUT + c) * HP + hp) * WP + t * 4;
    if (t < 15) {
        *(float4u*)op = (float4u){o[0], o[1], o[2], o[3]};
    } else {          // pooled cols 60,61,62 valid; 63 is pad
        op[0] = o[0]; op[1] = o[1]; op[2] = o[2];
    }
}

extern "C" void kernel_launch(void* const* d_in, const int* in_sizes, int n_in,
                              void* d_out, int out_size, void* d_ws, size_t ws_size,
                              hipStream_t stream) {
    const float* x      = (const float*)d_in[0];
    const float* conv_w = (const float*)d_in[1];
    const float* conv_b = (const float*)d_in[2];
    const float* gnw    = (const float*)d_in[3];
    const float* gnb    = (const float*)d_in[4];
    const float* scale  = (const float*)d_in[5];
    float* out = (float*)d_out;

    const size_t pl_bytes = (size_t)BATCH * COUT * HP * 64 * 4;   // 66.1 MB
    unsigned int* pl = (unsigned int*)d_ws;
    float* stats = (float*)((char*)d_ws + pl_bytes);              // 4 KB reserved
    _Float16* wT = (_Float16*)((char*)d_ws + pl_bytes + 4096);    // 147,456 B
    _Float16* xp = (_Float16*)((char*)d_ws + pl_bytes + 4096 + 147456); // 68.2 MB

    // prep: repack (x<128) + wt (x>=128) + stats zeroing, one launch
    dim3 pgrid(137, BATCH);
    prep_kernel<<<pgrid, 256, 0, stream>>>(x, conv_w, xp, wT, stats);

    dim3 grid(HP, BATCH);   // 63 x 32 = 2016 blocks
    conv_mfma_kernel<<<grid, 256, 0, stream>>>(xp, wT, conv_b, pl, stats);

    norm_pool_kernel<<<BATCH * COUT * 4, 256, 0, stream>>>(
        pl, stats, gnw, gnb, scale, out);
}

// Round 7
// 340.443 us; speedup vs baseline: 1.2651x; 1.0658x over previous
//
#include <hip/hip_runtime.h>

typedef _Float16 half8 __attribute__((ext_vector_type(8)));
typedef _Float16 half4t __attribute__((ext_vector_type(4)));
typedef _Float16 half2t __attribute__((ext_vector_type(2)));
typedef float float4t __attribute__((ext_vector_type(4)));
typedef float float4u __attribute__((ext_vector_type(4), aligned(4)));

#define BATCH 32
#define CIN 64
#define HIN 128
#define WIN 128
#define COUT 128
#define HOUT 126
#define WOUT 126
#define HP 63
#define WP 63
#define NGROUPS 16
#define CPG 8
#define EPSV 1e-5f

// xp row: 130 cols x 64 cins fp16 = 16640 B (8320 elems)
#define XPR 8320
#define XPRB 16640

// Fused prep kernel. grid (137, 32):
//   x < 128 : repack block (grow = x, b = y) — LDS-free transpose.
//   x >= 128: wt block (pos = x-128, grp = y); block (128,0) also zeroes stats.
__global__ __launch_bounds__(256) void prep_kernel(
    const float* __restrict__ x, const float* __restrict__ w,
    _Float16* __restrict__ xp, _Float16* __restrict__ wT,
    float* __restrict__ stats)
{
    const int tid = threadIdx.x;
    if (blockIdx.x >= 128) {
        // ---- weight transform: wT[pos][cout][cin] ----
        const int pos = blockIdx.x - 128;
        const int idx = blockIdx.y * 256 + tid;   // 0..8191 = cout*64+cin
        const int cout = idx >> 6, cin = idx & 63;
        wT[pos * (COUT * CIN) + idx] = (_Float16)w[(cout * CIN + cin) * 9 + pos];
        if (blockIdx.x == 128 && blockIdx.y == 0)
            ((float4t*)stats)[tid] = (float4t){0.f, 0.f, 0.f, 0.f};   // 1024 floats
        return;
    }

    const int grow = blockIdx.x;
    const int b = blockIdx.y;
    const int colq = tid >> 3;       // 0..31 -> cols 4*colq..4*colq+3
    const int chk  = tid & 7;        // cin chunk (8 cins)
    const int c0 = colq * 4;

    const float* xb = x + (((size_t)b * CIN + chk * 8) * HIN + grow) * WIN + c0;
    float4t v[8];
#pragma unroll
    for (int i = 0; i < 8; i++)
        v[i] = *(const float4t*)(xb + (size_t)i * HIN * WIN);

    _Float16* xpb = xp + ((size_t)b * HIN + grow) * XPR;
#pragma unroll
    for (int j = 0; j < 4; j++) {
        int col = c0 + j;
        int slot = chk ^ ((2 * grow + col) & 7);
        half8 h = { (_Float16)v[0][j], (_Float16)v[1][j], (_Float16)v[2][j],
                    (_Float16)v[3][j], (_Float16)v[4][j], (_Float16)v[5][j],
                    (_Float16)v[6][j], (_Float16)v[7][j] };
        *(half8*)(xpb + col * 64 + slot * 8) = h;   // 16B; 8 chk-lanes = 128B row
    }
    if (tid < 16) {                  // pad cols 128,129 = zeros
        int col = 128 + (tid >> 3), ck = tid & 7;
        int slot = ck ^ ((2 * grow + col) & 7);
        half8 z;
#pragma unroll
        for (int j = 0; j < 8; j++) z[j] = (_Float16)0.f;
        *(half8*)(xpb + col * 64 + slot * 8) = z;
    }
}

// Conv (R4/R6 dataflow + R7 scheduling): 2 output rows per block, 256 thr / 4 waves.
// Stage 4 xp rows (66,560 B), ONE barrier. kk loop FULLY UNROLLED with a 2-deep
// weight prefetch ring (a/na/nna) so ~2 kk of weight loads are always in flight
// (> L2 latency). s_setprio(1) around MFMA clusters: the 2 waves/SIMD belong to
// different blocks -> independent phases -> arbitration helps (T5).
__global__ __launch_bounds__(256, 2) void conv_mfma_kernel(
    const _Float16* __restrict__ xp, const _Float16* __restrict__ wT,
    const float* __restrict__ bias, unsigned int* __restrict__ pl,
    float* __restrict__ stats)
{
    __shared__ __align__(16) _Float16 xs[4 * XPR];   // 66,560 B

    const int tid = threadIdx.x;
    // XCD-chunked remap (bijective: 2016 = 8*252)
    int f = blockIdx.y * 63 + blockIdx.x;
    int w = (f & 7) * 252 + (f >> 3);
    const int s = w % 63;
    const int b = w / 63;
    const int oy = 2 * s;

    const int lane = tid & 63;
    const int wv = tid >> 6;
    const int w2 = wv & 1;        // cout half
    const int nh = wv >> 1;       // pixel half
    const int m = lane & 15;
    const int q = lane >> 4;
    const int cb = w2 * 64;

    // ---- stage: rows oy..oy+3 contiguous in xp -> linear 66,560B copy ----
    {
        const char* src = (const char*)(xp + ((size_t)b * HIN + oy) * XPR);
#pragma unroll
        for (int k = 0; k < 16; k++) {
            int chunk = wv * 16 + k;   // 0..63
            __builtin_amdgcn_global_load_lds(
                (const __attribute__((address_space(1))) void*)(src + chunk * 1024 + lane * 16),
                (__attribute__((address_space(3))) void*)((char*)xs + chunk * 1024), 16, 0, 0);
        }
        if (wv == 0) {
            __builtin_amdgcn_global_load_lds(
                (const __attribute__((address_space(1))) void*)(src + 65536 + lane * 16),
                (__attribute__((address_space(3))) void*)((char*)xs + 65536), 16, 0, 0);
        }
    }

    const _Float16* wBase = wT + (size_t)(cb + m) * CIN + q * 8;   // + pos*COUT*CIN + sub*16*CIN + ch*32

    half8 a[4], na[4], nna[4];
#pragma unroll
    for (int sub = 0; sub < 4; sub++) {
        a[sub]  = *(const half8*)(wBase + (size_t)sub * 16 * CIN);        // kk=0: pos0 ch0
        na[sub] = *(const half8*)(wBase + (size_t)sub * 16 * CIN + 32);   // kk=1: pos0 ch1
    }

    float bv[4];
#pragma unroll
    for (int sub = 0; sub < 4; sub++) bv[sub] = bias[cb + sub * 16 + m];

    float4t acc0[4][4], acc1[4][4];
#pragma unroll
    for (int sub = 0; sub < 4; sub++)
#pragma unroll
        for (int n = 0; n < 4; n++) {
            acc0[sub][n] = (float4t){0.f, 0.f, 0.f, 0.f};
            acc1[sub][n] = (float4t){0.f, 0.f, 0.f, 0.f};
        }

    __syncthreads();

#pragma unroll
    for (int kk = 0; kk < 18; kk++) {
        const int pos = kk >> 1, ch = kk & 1;
        const int kh = (pos > 2) + (pos > 5);
        const int kw = pos - kh * 3;
        int key0 = (2 * (oy + kh) + m + kw) & 7;        // row oy+kh   -> xs[kh]
        int key1 = (key0 + 2) & 7;                      // row oy+1+kh -> xs[kh+1]
        const _Float16* b0 = &xs[kh * XPR + (m + kw) * 64 + (((q + 4 * ch) ^ key0) << 3)];
        const _Float16* b1 = &xs[(kh + 1) * XPR + (m + kw) * 64 + (((q + 4 * ch) ^ key1) << 3)];

        // 2-deep ring: issue kk+2's weight loads now (in flight across this kk's MFMAs)
        const int nk = (kk < 16) ? kk + 2 : 0;
        const int npos = nk >> 1, nch = nk & 1;
#pragma unroll
        for (int sub = 0; sub < 4; sub++)
            nna[sub] = *(const half8*)(wBase + (size_t)npos * COUT * CIN
                                       + (size_t)sub * 16 * CIN + nch * 32);

        __builtin_amdgcn_s_setprio(1);
#pragma unroll
        for (int n = 0; n < 4; n++) {
            half8 bf0 = *(const half8*)(b0 + (nh * 4 + n) * 1024);
            half8 bf1 = *(const half8*)(b1 + (nh * 4 + n) * 1024);
#pragma unroll
            for (int sub = 0; sub < 4; sub++) {
                acc0[sub][n] = __builtin_amdgcn_mfma_f32_16x16x32_f16(bf0, a[sub], acc0[sub][n], 0, 0, 0);
                acc1[sub][n] = __builtin_amdgcn_mfma_f32_16x16x32_f16(bf1, a[sub], acc1[sub][n], 0, 0, 0);
            }
        }
        __builtin_amdgcn_s_setprio(0);
#pragma unroll
        for (int sub = 0; sub < 4; sub++) { a[sub] = na[sub]; na[sub] = nna[sub]; }
    }

    // ---- epilogue: bias, stats (both rows), 2x2 pool -> {max,min} fp16 pairs ----
    float sv[4] = {0.f, 0.f, 0.f, 0.f}, ssv[4] = {0.f, 0.f, 0.f, 0.f};
#pragma unroll
    for (int sub = 0; sub < 4; sub++) {
        const int c = cb + sub * 16 + m;
#pragma unroll
        for (int n = 0; n < 4; n++) {
            int pix0 = (nh * 4 + n) * 16 + q * 4;
            float p00 = acc0[sub][n][0] + bv[sub];
            float p01 = acc0[sub][n][1] + bv[sub];
            float p02 = acc0[sub][n][2] + bv[sub];
            float p03 = acc0[sub][n][3] + bv[sub];
            float p10 = acc1[sub][n][0] + bv[sub];
            float p11 = acc1[sub][n][1] + bv[sub];
            float p12 = acc1[sub][n][2] + bv[sub];
            float p13 = acc1[sub][n][3] + bv[sub];
            sv[sub]  += p00 + p01 + p10 + p11;
            ssv[sub] += p00 * p00 + p01 * p01 + p10 * p10 + p11 * p11;
            if (pix0 != 124) {      // only (nh=1,n=3,q=3): pixels 126/127 invalid
                sv[sub]  += p02 + p03 + p12 + p13;
                ssv[sub] += p02 * p02 + p03 * p03 + p12 * p12 + p13 * p13;
            }
            float mx0 = fmaxf(fmaxf(p00, p01), fmaxf(p10, p11));
            float mn0 = fminf(fminf(p00, p01), fminf(p10, p11));
            float mx1 = fmaxf(fmaxf(p02, p03), fmaxf(p12, p13));
            float mn1 = fminf(fminf(p02, p03), fminf(p12, p13));
            half4t o = { (_Float16)mx0, (_Float16)mn0, (_Float16)mx1, (_Float16)mn1 };
            unsigned int* dst = pl + (((size_t)b * COUT + c) * HP + s) * 64
                                + (nh * 4 + n) * 8 + 2 * q;
            *(half4t*)dst = o;      // 8B; pooled col 63 garbage, never read
        }
    }

    // ---- stats: reduce over lane bits {0,1,2,4,5}, atomic once per block ----
#pragma unroll
    for (int sub = 0; sub < 4; sub++) {
        float aa = sv[sub], cc = ssv[sub];
        aa += __shfl_xor(aa, 1);  cc += __shfl_xor(cc, 1);
        aa += __shfl_xor(aa, 2);  cc += __shfl_xor(cc, 2);
        aa += __shfl_xor(aa, 4);  cc += __shfl_xor(cc, 4);
        aa += __shfl_xor(aa, 16); cc += __shfl_xor(cc, 16);
        aa += __shfl_xor(aa, 32); cc += __shfl_xor(cc, 32);
        if ((lane & 55) == 0) {   // lanes 0 and 8
            int g = w2 * 8 + sub * 2 + ((lane >> 3) & 1);
            atomicAdd(&stats[(b * NGROUPS + g) * 2 + 0], aa);
            atomicAdd(&stats[(b * NGROUPS + g) * 2 + 1], cc);
        }
    }
}

// pl entry = half2 {mx, mn} per pooled col. out = max(A*mx+B, A*mn+B): exact for
// either sign of A.
__global__ __launch_bounds__(256) void norm_pool_kernel(
    const unsigned int* __restrict__ pl, const float* __restrict__ stats,
    const float* __restrict__ gnw, const float* __restrict__ gnb,
    const float* __restrict__ scale, float* __restrict__ out)
{
    const int t  = threadIdx.x & 15;        // pooled cols 4t..4t+3
    const int hs = threadIdx.x >> 4;
    const int hblk = blockIdx.x & 3;
    const int c = (blockIdx.x >> 2) & 127;
    const int b = blockIdx.x >> 9;
    const int hp = hblk * 16 + hs;

    const float N = (float)(CPG * HOUT * WOUT);
    int g = c >> 3;
    float sum   = stats[(b * NGROUPS + g) * 2 + 0];
    float sumsq = stats[(b * NGROUPS + g) * 2 + 1];
    float mean = sum / N;
    float var  = sumsq / N - mean * mean;
    float rstd = rsqrtf(var + EPSV);

    float gw = gnw[c] * rstd;
    float A  = gw * scale[c];
    float B2 = (gnb[c] - mean * gw) * scale[c];

    if (hp >= HP) return;

    const unsigned int* yp = pl + (((size_t)b * COUT + c) * HP + hp) * 64 + t * 4;
    half8 rv = *(const half8*)yp;   // 4 entries = {mx,mn}x4

    float o[4];
#pragma unroll
    for (int j = 0; j < 4; j++) {
        float vx = fmaf((float)rv[2 * j],     A, B2);
        float vn = fmaf((float)rv[2 * j + 1], A, B2);
        float mx = fmaxf(vx, vn);
        o[j] = fminf(fmaxf(mx, 0.0f), 1.0f);
    }

    float* op = out + (((size_t)b * COUT + c) * HP + hp) * WP + t * 4;
    if (t < 15) {
        *(float4u*)op = (float4u){o[0], o[1], o[2], o[3]};
    } else {          // pooled cols 60,61,62 valid; 63 is pad
        op[0] = o[0]; op[1] = o[1]; op[2] = o[2];
    }
}

extern "C" void kernel_launch(void* const* d_in, const int* in_sizes, int n_in,
                              void* d_out, int out_size, void* d_ws, size_t ws_size,
                              hipStream_t stream) {
    const float* x      = (const float*)d_in[0];
    const float* conv_w = (const float*)d_in[1];
    const float* conv_b = (const float*)d_in[2];
    const float* gnw    = (const float*)d_in[3];
    const float* gnb    = (const float*)d_in[4];
    const float* scale  = (const float*)d_in[5];
    float* out = (float*)d_out;

    const size_t pl_bytes = (size_t)BATCH * COUT * HP * 64 * 4;   // 66.1 MB
    unsigned int* pl = (unsigned int*)d_ws;
    float* stats = (float*)((char*)d_ws + pl_bytes);              // 4 KB reserved
    _Float16* wT = (_Float16*)((char*)d_ws + pl_bytes + 4096);    // 147,456 B
    _Float16* xp = (_Float16*)((char*)d_ws + pl_bytes + 4096 + 147456); // 68.2 MB

    // prep: repack (x<128) + wt (x>=128) + stats zeroing, one launch
    dim3 pgrid(137, BATCH);
    prep_kernel<<<pgrid, 256, 0, stream>>>(x, conv_w, xp, wT, stats);

    dim3 grid(HP, BATCH);   // 63 x 32 = 2016 blocks
    conv_mfma_kernel<<<grid, 256, 0, stream>>>(xp, wT, conv_b, pl, stats);

    norm_pool_kernel<<<BATCH * COUT * 4, 256, 0, stream>>>(
        pl, stats, gnw, gnb, scale, out);
}